// Round 13
// baseline (1191.217 us; speedup 1.0000x reference)
//
#include <hip/hip_runtime.h>

// GraphSAGE stack on MI355X — round 13: r12 structure + BARRIER-FREE phase 1
// in k_fuse2: per-wave direct global->register MFMA fragments (no As/Bs staging,
// no phase-1 barriers). Phase 2 (T exchange + LDS-staged weights) unchanged r8.
// Row order m = 4n+b. f16 activations, fp32 accumulate.

#define NN 55296
#define MM (NN * 4)   // 221184 rows

typedef unsigned short u16;
typedef _Float16 f16;
typedef f16 f16x8 __attribute__((ext_vector_type(8)));
typedef float f32x4 __attribute__((ext_vector_type(4)));
typedef u16 u16x8 __attribute__((ext_vector_type(8)));

__device__ inline u16 f2h(float f) { return __builtin_bit_cast(u16, (f16)f); }
__device__ inline float h2f(u16 u) { return (float)__builtin_bit_cast(f16, u); }
__device__ inline f16x8 ldh8(const u16* p) {
  return __builtin_bit_cast(f16x8, *(const u16x8*)p);
}

// ---------------------------------------------------------------- diagnostics
__global__ __launch_bounds__(256) void k_fill(float* __restrict__ p, float v, int total) {
  int i = blockIdx.x * 256 + threadIdx.x;
  if (i < total) p[i] = v;
}

// ---------------------------------------------------------------- input prep
__global__ __launch_bounds__(256) void k_prep_x(const float* __restrict__ in,
                                                u16* __restrict__ out) {
  int idx = blockIdx.x * 256 + threadIdx.x;
  int n = idx >> 5, b = (idx >> 3) & 3, f0 = (idx & 7) * 8;
  const float* p = in + ((long)b * NN + n) * 64 + f0;
  float4 v0 = *(const float4*)p, v1 = *(const float4*)(p + 4);
  u16x8 r;
  r[0] = f2h(v0.x); r[1] = f2h(v0.y); r[2] = f2h(v0.z); r[3] = f2h(v0.w);
  r[4] = f2h(v1.x); r[5] = f2h(v1.y); r[6] = f2h(v1.z); r[7] = f2h(v1.w);
  *(u16x8*)(out + (((long)n * 4 + b) * 64 + f0)) = r;
}

// ---------------------------------------------------------------- weight prep
// fused layout: dst[n][k'] = k'<K ? ws[k'][n] : wn[k'-K][n]  ([N][2K])
__global__ __launch_bounds__(256) void k_prep_w(const float* __restrict__ wsrc,
                                                const float* __restrict__ wnsrc,
                                                int K, int N, u16* __restrict__ dst) {
  int idx = blockIdx.x * 256 + threadIdx.x;
  int K2 = 2 * K;
  if (idx >= N * K2) return;
  int n = idx / K2, k = idx - n * K2;
  float v = (k < K) ? wsrc[(long)k * N + n] : wnsrc[(long)(k - K) * N + n];
  dst[(long)n * K2 + k] = f2h(v);
}

// dual layout: dst[r][k], r<N -> ws col r; r>=N -> wn col r-N  ([2N][K])
__global__ __launch_bounds__(256) void k_prep_w2(const float* __restrict__ wsrc,
                                                 const float* __restrict__ wnsrc,
                                                 int K, int N, u16* __restrict__ dst) {
  int idx = blockIdx.x * 256 + threadIdx.x;
  int total = 2 * N * K;
  if (idx >= total) return;
  int r = idx / K, k = idx - r * K;
  float v = (r < N) ? wsrc[(long)k * N + r] : wnsrc[(long)k * N + (r - N)];
  dst[idx] = f2h(v);
}

// ---------------------------------------------------------------- r8 SAGE/dense GEMM
template <int BM, int BN, int WM, int WN, typename TOUT, bool REMAP, bool GATHER>
__global__ __launch_bounds__(512, 4) void k_sage(
    const u16* __restrict__ X0, const u16* __restrict__ X1, int lda, int K0, int Ksum,
    const int4* __restrict__ src4, const u16* __restrict__ Wt,
    const float* __restrict__ bias, TOUT* __restrict__ OUT, long ldo,
    TOUT* __restrict__ OUT2, long ldo2, int Nsplit, int relu) {
  constexpr int GA = BM / 64;
  constexpr int GB = BN / 64;
  constexpr int NWM = BM / WM, NWN = BN / WN;
  static_assert(NWM * NWN == 8, "8 waves");
  constexpr int MF = WM / 16, NF = WN / 16;

  __shared__ __align__(16) u16 As[BM][64];
  __shared__ __align__(16) u16 Bs[BN][64];

  const int tid = threadIdx.x;
  const long m0 = (long)blockIdx.x * BM;
  const int n0 = blockIdx.y * BN;
  const int K2 = GATHER ? 2 * Ksum : Ksum;

  const int srow = tid >> 3;
  const int scg = tid & 7;

  int o_self[GA], o_g[GA][4];
#pragma unroll
  for (int i = 0; i < GA; ++i) {
    long m = m0 + srow + 64 * i;
    o_self[i] = (int)(m * lda);
    if constexpr (GATHER) {
      int b = (int)(m & 3);
      int4 s = src4[(int)(m >> 2)];
      o_g[i][0] = (s.x * 4 + b) * lda;
      o_g[i][1] = (s.y * 4 + b) * lda;
      o_g[i][2] = (s.z * 4 + b) * lda;
      o_g[i][3] = (s.w * 4 + b) * lda;
    }
  }
  long o_b[GB];
#pragma unroll
  for (int j = 0; j < GB; ++j) o_b[j] = (long)(n0 + srow + 64 * j) * K2 + scg * 8;

  u16x8 ra[GA][4];
  u16x8 rb[GB];

  const int w = tid >> 6, lane = tid & 63;
  const int wm = w % NWM, wn = w / NWM;
  const int mo = wm * WM, no = wn * WN;
  const int lr = lane & 15, lg = lane >> 4;

  f32x4 acc[MF][NF];
#pragma unroll
  for (int i = 0; i < MF; ++i)
#pragma unroll
    for (int j = 0; j < NF; ++j) {
      f32x4 z = {0.f, 0.f, 0.f, 0.f};
      acc[i][j] = z;
    }

  auto issue = [&](int kt) {
    const bool agg = GATHER && (kt >= Ksum);
    int cs = agg ? kt - Ksum : kt;
    const u16* Xp = X0;
    if (cs >= K0) { Xp = X1; cs -= K0; }
    const int cb = cs + scg * 8;
#pragma unroll
    for (int i = 0; i < GA; ++i) {
      if (agg) {
#pragma unroll
        for (int k = 0; k < 4; ++k)
          ra[i][k] = *(const u16x8*)(Xp + (long)o_g[i][k] + cb);
      } else {
        ra[i][0] = *(const u16x8*)(Xp + (long)o_self[i] + cb);
      }
    }
#pragma unroll
    for (int j = 0; j < GB; ++j)
      rb[j] = *(const u16x8*)(Wt + o_b[j] + kt);
  };
  auto commit = [&](bool agg) {
#pragma unroll
    for (int i = 0; i < GA; ++i) {
      const int row = srow + 64 * i;
      u16x8 v = ra[i][0];
      if (agg) {
        f16x8 s01 = __builtin_bit_cast(f16x8, ra[i][0]) + __builtin_bit_cast(f16x8, ra[i][1]);
        f16x8 s23 = __builtin_bit_cast(f16x8, ra[i][2]) + __builtin_bit_cast(f16x8, ra[i][3]);
        v = __builtin_bit_cast(u16x8, (s01 + s23) * (f16)0.25f);
      }
      *(u16x8*)&As[row][(scg ^ (row & 7)) * 8] = v;
    }
#pragma unroll
    for (int j = 0; j < GB; ++j) {
      const int row = srow + 64 * j;
      *(u16x8*)&Bs[row][(scg ^ (row & 7)) * 8] = rb[j];
    }
  };

  issue(0);
  for (int kt = 0; kt < K2; kt += 64) {
    commit(GATHER && kt >= Ksum);
    __syncthreads();
    const int nx = kt + 64;
    if (nx < K2) issue(nx);
#pragma unroll
    for (int ks = 0; ks < 2; ++ks) {
      f16x8 af[MF], bfr[NF];
#pragma unroll
      for (int i = 0; i < MF; ++i) {
        const int row = mo + i * 16 + lr;
        af[i] = __builtin_bit_cast(f16x8,
                  *(const u16x8*)&As[row][((ks * 4 + lg) ^ (row & 7)) * 8]);
      }
#pragma unroll
      for (int j = 0; j < NF; ++j) {
        const int row = no + j * 16 + lr;
        bfr[j] = __builtin_bit_cast(f16x8,
                   *(const u16x8*)&Bs[row][((ks * 4 + lg) ^ (row & 7)) * 8]);
      }
#pragma unroll
      for (int i = 0; i < MF; ++i)
#pragma unroll
        for (int j = 0; j < NF; ++j)
          acc[i][j] = __builtin_amdgcn_mfma_f32_16x16x32_f16(af[i], bfr[j], acc[i][j], 0, 0, 0);
    }
    __syncthreads();
  }

#pragma unroll
  for (int i = 0; i < MF; ++i)
#pragma unroll
    for (int j = 0; j < NF; ++j) {
      const int col = n0 + no + j * 16 + lr;
      const float bv = bias ? bias[col] : 0.f;
      TOUT* Op; long ld; int c;
      if (col < Nsplit) { Op = OUT; ld = ldo; c = col; }
      else              { Op = OUT2; ld = ldo2; c = col - Nsplit; }
#pragma unroll
      for (int r = 0; r < 4; ++r) {
        float v = acc[i][j][r] + bv;
        if (relu) v = fmaxf(v, 0.f);
        const long m = m0 + mo + i * 16 + lg * 4 + r;
        const long orow = REMAP ? ((m & 3) * (long)NN + (m >> 2)) : m;
        if constexpr (sizeof(TOUT) == 2) Op[orow * ld + c] = (TOUT)f2h(v);
        else                             Op[orow * ld + c] = v;
      }
    }
}

// ---------------------------------------------------------------- two-phase fusion
// Phase1 (BARRIER-FREE): per-wave direct global->reg fragments,
//   T(64 x N1) = relu( [X|mean4 gather X] @ W1t^T + bias1 )  -> T in LDS.
// Phase2: [OUT|OUT2] = [T | G2(own rows)] @ W2t^T (LDS-staged weights, r8).
template <int N1, int KS1, int K2B, int N2, int NSPLIT>
__global__ __launch_bounds__(512, 4) void k_fuse2(
    const u16* __restrict__ X0, const u16* __restrict__ X1, int lda, int K0,
    const int4* __restrict__ src4,
    const u16* __restrict__ W1t, const float* __restrict__ bias1,
    const u16* __restrict__ G2, int ldg2,
    const u16* __restrict__ W2t,
    u16* __restrict__ OUT, long ldo, u16* __restrict__ OUT2, long ldo2) {
  constexpr int K21 = 2 * KS1;          // phase1 K (self + agg)
  constexpr int K22 = N1 + K2B;         // phase2 K
  constexpr int GB2 = N2 / 64;
  __shared__ __align__(16) u16 T[64][N1];
  __shared__ __align__(16) u16 Bs[N2][64];
  __shared__ __align__(16) u16 As[(K2B > 0) ? 64 : 1][64];   // G2 staging only

  const int tid = threadIdx.x;
  const long m0 = (long)blockIdx.x * 64;
  const int srow = tid >> 3, scg = tid & 7;
  const long mrow = m0 + srow;

  const int w = tid >> 6, lane = tid & 63;
  const int lr = lane & 15, lg = lane >> 4;

  // ---------------- phase 1: direct-register fused gather GEMM (no barriers)
  constexpr int NWN1 = N1 / 32, NWM1 = 8 / NWN1, WM1 = 64 / NWM1, MF1 = WM1 / 16;
  const int mo1 = (w % NWM1) * WM1, no1 = (w / NWM1) * 32;

  long aoff[MF1]; int goff[MF1][4];
#pragma unroll
  for (int i = 0; i < MF1; ++i) {
    const long m = m0 + mo1 + i * 16 + lr;
    aoff[i] = m * lda;
    const int b = (int)(m & 3);
    const int4 s = src4[(int)(m >> 2)];
    goff[i][0] = (s.x * 4 + b) * lda;
    goff[i][1] = (s.y * 4 + b) * lda;
    goff[i][2] = (s.z * 4 + b) * lda;
    goff[i][3] = (s.w * 4 + b) * lda;
  }

  f32x4 acc1[MF1][2];
#pragma unroll
  for (int i = 0; i < MF1; ++i) {
    f32x4 z = {0.f, 0.f, 0.f, 0.f};
    acc1[i][0] = z; acc1[i][1] = z;
  }

#pragma unroll
  for (int kt = 0; kt < K21; kt += 32) {
    const bool agg = kt >= KS1;
    int cs = agg ? kt - KS1 : kt;
    const u16* Xp = X0;
    if (cs >= K0) { Xp = X1; cs -= K0; }
    const int c = cs + lg * 8;
    f16x8 af[MF1];
#pragma unroll
    for (int i = 0; i < MF1; ++i) {
      if (agg) {
        f16x8 g0 = ldh8(Xp + goff[i][0] + c);
        f16x8 g1 = ldh8(Xp + goff[i][1] + c);
        f16x8 g2 = ldh8(Xp + goff[i][2] + c);
        f16x8 g3 = ldh8(Xp + goff[i][3] + c);
        af[i] = ((g0 + g1) + (g2 + g3)) * (f16)0.25f;
      } else {
        af[i] = ldh8(Xp + aoff[i] + c);
      }
    }
    const long wc = kt + lg * 8;
    f16x8 bf0 = ldh8(W1t + (long)(no1 + lr) * K21 + wc);
    f16x8 bf1 = ldh8(W1t + (long)(no1 + 16 + lr) * K21 + wc);
#pragma unroll
    for (int i = 0; i < MF1; ++i) {
      acc1[i][0] = __builtin_amdgcn_mfma_f32_16x16x32_f16(af[i], bf0, acc1[i][0], 0, 0, 0);
      acc1[i][1] = __builtin_amdgcn_mfma_f32_16x16x32_f16(af[i], bf1, acc1[i][1], 0, 0, 0);
    }
  }

  // epilogue1: relu+bias -> T (granule-swizzled), C/D layout per m89
#pragma unroll
  for (int i = 0; i < MF1; ++i)
#pragma unroll
    for (int j = 0; j < 2; ++j) {
      const int col = no1 + j * 16 + lr;
      const float bv = bias1[col];
#pragma unroll
      for (int r = 0; r < 4; ++r) {
        float v = fmaxf(acc1[i][j][r] + bv, 0.f);
        const int row = mo1 + i * 16 + lg * 4 + r;
        T[row][(((col >> 3) ^ (row & 7)) << 3) | (col & 7)] = f2h(v);
      }
    }

  // ---------------- phase 2: dense dual GEMM [T | G2] @ W2t (r8 structure)
  constexpr int NWN2 = N2 / 32, NWM2 = 8 / NWN2, WM2 = 64 / NWM2, MF2 = WM2 / 16;
  const int mo2 = (w % NWM2) * WM2, no2 = (w / NWM2) * 32;

  long ob2[GB2];
#pragma unroll
  for (int j = 0; j < GB2; ++j) ob2[j] = (long)(srow + 64 * j) * K22 + scg * 8;
  const long oG = (K2B > 0) ? (mrow * (long)ldg2 + scg * 8) : 0;

  u16x8 rb2[GB2], rg;

  auto issue2 = [&](int kt) {
#pragma unroll
    for (int j = 0; j < GB2; ++j)
      rb2[j] = *(const u16x8*)(W2t + ob2[j] + kt);
    if constexpr (K2B > 0) {
      if (kt >= N1) rg = *(const u16x8*)(G2 + oG + (kt - N1));
    }
  };
  auto commit2 = [&](int kt) {
#pragma unroll
    for (int j = 0; j < GB2; ++j) {
      const int row = srow + 64 * j;
      *(u16x8*)&Bs[row][(scg ^ (row & 7)) * 8] = rb2[j];
    }
    if constexpr (K2B > 0) {
      if (kt >= N1) *(u16x8*)&As[srow][(scg ^ (srow & 7)) * 8] = rg;
    }
  };

  f32x4 acc2[MF2][2];
#pragma unroll
  for (int i = 0; i < MF2; ++i) {
    f32x4 z = {0.f, 0.f, 0.f, 0.f};
    acc2[i][0] = z; acc2[i][1] = z;
  }

  issue2(0);
  for (int kt = 0; kt < K22; kt += 64) {
    commit2(kt);
    __syncthreads();                     // first iter also publishes T
    if (kt + 64 < K22) issue2(kt + 64);
    const bool fromT = kt < N1;
#pragma unroll
    for (int ks = 0; ks < 2; ++ks) {
      f16x8 af[MF2], bf0, bf1;
#pragma unroll
      for (int i = 0; i < MF2; ++i) {
        const int row = mo2 + i * 16 + lr;
        if (fromT) {
          const int g = (kt >> 3) + ks * 4 + lg;
          af[i] = __builtin_bit_cast(f16x8,
                    *(const u16x8*)&T[row][(g ^ (row & 7)) * 8]);
        } else {
          af[i] = __builtin_bit_cast(f16x8,
                    *(const u16x8*)&As[row][((ks * 4 + lg) ^ (row & 7)) * 8]);
        }
      }
      {
        const int row = no2 + lr;
        bf0 = __builtin_bit_cast(f16x8,
                *(const u16x8*)&Bs[row][((ks * 4 + lg) ^ (row & 7)) * 8]);
      }
      {
        const int row = no2 + 16 + lr;
        bf1 = __builtin_bit_cast(f16x8,
                *(const u16x8*)&Bs[row][((ks * 4 + lg) ^ (row & 7)) * 8]);
      }
#pragma unroll
      for (int i = 0; i < MF2; ++i) {
        acc2[i][0] = __builtin_amdgcn_mfma_f32_16x16x32_f16(af[i], bf0, acc2[i][0], 0, 0, 0);
        acc2[i][1] = __builtin_amdgcn_mfma_f32_16x16x32_f16(af[i], bf1, acc2[i][1], 0, 0, 0);
      }
    }
    __syncthreads();
  }

  // epilogue2: split-routed store, no bias/relu (applied in k_gadd)
#pragma unroll
  for (int i = 0; i < MF2; ++i)
#pragma unroll
    for (int j = 0; j < 2; ++j) {
      const int col = no2 + j * 16 + lr;
      u16* Op; long ld; int c;
      if (col < NSPLIT) { Op = OUT; ld = ldo; c = col; }
      else              { Op = OUT2; ld = ldo2; c = col - NSPLIT; }
#pragma unroll
      for (int r = 0; r < 4; ++r) {
        const long m = m0 + mo2 + i * 16 + lg * 4 + r;
        Op[m * ld + c] = f2h(acc2[i][j][r]);
      }
    }
}

// ---------------------------------------------------------------- gather-add pass
template <typename TOUT, bool REMAP, bool RELU, int GSH>
__global__ __launch_bounds__(256) void k_gadd(
    const u16* __restrict__ Y, long ldy, const u16* __restrict__ Z, long ldz,
    const int4* __restrict__ src4, const float* __restrict__ bias,
    TOUT* __restrict__ OUT, long ldo) {
  const int idx = blockIdx.x * 256 + threadIdx.x;
  const int g = idx & ((1 << GSH) - 1);
  const long m = idx >> GSH;
  const int b = (int)(m & 3), n = (int)(m >> 2);
  const int4 s = src4[n];
  u16x8 ys = *(const u16x8*)(Y + m * ldy + g * 8);
  u16x8 z0 = *(const u16x8*)(Z + (long)(s.x * 4 + b) * ldz + g * 8);
  u16x8 z1 = *(const u16x8*)(Z + (long)(s.y * 4 + b) * ldz + g * 8);
  u16x8 z2 = *(const u16x8*)(Z + (long)(s.z * 4 + b) * ldz + g * 8);
  u16x8 z3 = *(const u16x8*)(Z + (long)(s.w * 4 + b) * ldz + g * 8);
  float4 bv0 = *(const float4*)(bias + g * 8);
  float4 bv1 = *(const float4*)(bias + g * 8 + 4);
  float o[8];
#pragma unroll
  for (int j = 0; j < 8; ++j) {
    float bj = (j < 4) ? (&bv0.x)[j] : (&bv1.x)[j - 4];
    float v = h2f(ys[j]) + 0.25f * (h2f(z0[j]) + h2f(z1[j]) + h2f(z2[j]) + h2f(z3[j])) + bj;
    o[j] = RELU ? fmaxf(v, 0.f) : v;
  }
  const long orow = REMAP ? ((long)b * NN + n) : m;
  if constexpr (sizeof(TOUT) == 2) {
    u16x8 r;
#pragma unroll
    for (int j = 0; j < 8; ++j) r[j] = f2h(o[j]);
    *(u16x8*)(OUT + orow * ldo + g * 8) = r;
  } else {
#pragma unroll
    for (int j = 0; j < 8; ++j) OUT[orow * ldo + g * 8 + j] = o[j];
  }
}

// ---------------------------------------------------------------- host driver
extern "C" void kernel_launch(void* const* d_in, const int* in_sizes, int n_in,
                              void* d_out, int out_size, void* d_ws, size_t ws_size,
                              hipStream_t stream) {
  const float* inputs = (const float*)d_in[0];
  const int*   src    = (const int*)d_in[1];
  const float* W[6][3];
  for (int i = 0; i < 6; ++i) {
    W[i][0] = (const float*)d_in[3 + 3 * i];
    W[i][1] = (const float*)d_in[4 + 3 * i];
    W[i][2] = (const float*)d_in[5 + 3 * i];
  }

  const long M = (long)MM;
  const int dims[6][2] = {{64,256},{256,128},{128,64},{64,64},{128,128},{256,64}};
  long wo[6]; long wtot = 0;
  for (int i = 0; i < 6; ++i) { wo[i] = wtot; wtot += (long)dims[i][1] * 2 * dims[i][0]; }
  const long woD3 = wtot;               // dual layout of weight 3 ([128][64])
  wtot += 2L * dims[3][1] * dims[3][0];

  const size_t needed = ((size_t)384 * M + wtot) * sizeof(u16);
  if (ws_size < needed) {
    float mb = (float)(ws_size >> 20);   // diagnostic: absmax ~= ws MiB
    k_fill<<<(out_size + 255) / 256, 256, 0, stream>>>((float*)d_out, mb, out_size);
    return;
  }

  u16* act = (u16*)d_ws;
  // slab plan (f16 cols of M), lifetimes audited disjoint (r12, proven):
  u16* Y1  = act + 0 * M;     // [M][128] K_AB out; becomes H2 in-place
  u16* H2  = act + 0 * M;     // [M][128] gadd1 -> K_FG phase2
  u16* Z1  = act + 128 * M;   // [M][128] K_AB out, dead after gadd1
  u16* YZ2 = act + 128 * M;   // [M][128] L2dense -> gadd2 (over Z1)
  u16* Z4  = act + 128 * M;   // [M][64]  K_CD out (YZ2 dead after gadd2)
  u16* Y6  = act + 128 * M;   // [M][64]  K_FG out (Z4 dead after gadd4)
  u16* H5a = act + 192 * M;   // [M][64]  gadd4 -> K_FG (YZ2 upper half dead)
  u16* H3  = act + 256 * M;   // [M][64]  gadd2 -> K_CD/K_FG
  u16* Xb  = act + 320 * M;   // [M][64]  f16 input (step0; dead after K_AB)
  u16* Y4  = act + 320 * M;   // [M][64]  K_CD out (over Xb)
  u16* Z6  = act + 320 * M;   // [M][64]  K_FG out (Y4 dead after gadd4)
  u16* WT  = act + 384 * M;   // packed weights
  u16* Xp  = (u16*)d_out;     // [M][64]  x' between steps (d_out scratch)
  const int4* src4 = (const int4*)src;

  k_prep_x<<<NN * 32 / 256, 256, 0, stream>>>(inputs, Xb);
  for (int i : {0, 3, 4}) {   // fused layouts (gather-phase B operands)
    int total = dims[i][1] * 2 * dims[i][0];
    k_prep_w<<<(total + 255) / 256, 256, 0, stream>>>(W[i][0], W[i][1], dims[i][0],
                                                      dims[i][1], WT + wo[i]);
  }
  for (int i : {1, 2, 5}) {   // dual layouts (dense dual GEMMs)
    int total = 2 * dims[i][1] * dims[i][0];
    k_prep_w2<<<(total + 255) / 256, 256, 0, stream>>>(W[i][0], W[i][1], dims[i][0],
                                                       dims[i][1], WT + wo[i]);
  }
  {  // dual layout of weight 3 for K_CD phase2
    int total = 2 * dims[3][1] * dims[3][0];
    k_prep_w2<<<(total + 255) / 256, 256, 0, stream>>>(W[3][0], W[3][1], dims[3][0],
                                                       dims[3][1], WT + woD3);
  }

  const int BIG = 1 << 30;
  const dim3 g1(MM / 128, 1);
  for (int step = 0; step < 2; ++step) {
    const u16* x0 = step ? Xp : Xb;
    // K_AB: L0 (x -> h1 tile, relu+b0) + L1 dense dual -> Y1 | Z1
    k_fuse2<256, 64, 0, 256, 128><<<MM / 64, 512, 0, stream>>>(
        x0, x0, 64, 64, src4, WT + wo[0], W[0][2],
        nullptr, 0, WT + wo[1], Y1, 128, Z1, 128);
    // gadd1: H2 = relu(Y1 + mean4 Z1[g] + b1)   (in-place over Y1)
    k_gadd<u16, false, true, 4><<<MM * 16 / 256, 256, 0, stream>>>(
        Y1, 128, Z1, 128, src4, W[1][2], H2, 128);
    // L2 dense dual: H2 -> YZ2 [Y|Z]
    k_sage<128, 128, 64, 32, u16, false, false><<<g1, 512, 0, stream>>>(
        H2, H2, 128, 128, 128, src4, WT + wo[2], nullptr, YZ2, 128,
        (u16*)nullptr, 0, BIG, 0);
    // gadd2: H3 = relu(Y + mean4 Z[g] + b2)
    k_gadd<u16, false, true, 3><<<MM * 8 / 256, 256, 0, stream>>>(
        YZ2, 128, YZ2 + 64, 128, src4, W[2][2], H3, 64);
    // K_CD: L3 (h3 -> h4 tile, relu+b3) + L4 dense dual h4@[Ws4|Wn4] -> Y4 | Z4
    k_fuse2<64, 64, 0, 128, 64><<<MM / 64, 512, 0, stream>>>(
        H3, H3, 64, 64, src4, WT + wo[3], W[3][2],
        nullptr, 0, WT + woD3, Y4, 64, Z4, 64);
    // gadd4: H5a = relu(Y4 + mean4 Z4[g] + b4)
    k_gadd<u16, false, true, 3><<<MM * 8 / 256, 256, 0, stream>>>(
        Y4, 64, Z4, 64, src4, W[3][2], H5a, 64);
    // K_FG: L5 ([h5a|h3] -> h6a tile, relu+b4) + L6 dense dual [tile|H2] -> Y6 | Z6
    k_fuse2<128, 128, 128, 128, 64><<<MM / 64, 512, 0, stream>>>(
        H5a, H3, 64, 64, src4, WT + wo[4], W[4][2],
        H2, 128, WT + wo[5], Y6, 64, Z6, 64);
    // gadd6: x' = Y6 + mean4 Z6[g] + b6  (no relu)
    if (step == 0)
      k_gadd<u16, false, false, 3><<<MM * 8 / 256, 256, 0, stream>>>(
          Y6, 64, Z6, 64, src4, W[5][2], Xp, 64);
    else
      k_gadd<float, true, false, 3><<<MM * 8 / 256, 256, 0, stream>>>(
          Y6, 64, Z6, 64, src4, W[5][2], (float*)d_out, 64);
  }
}

// Round 14
// 647.739 us; speedup vs baseline: 1.8390x; 1.8390x over previous
//
#include <hip/hip_runtime.h>

// GraphSAGE stack on MI355X — round 14: exact revert to r12 (best: 648.7us).
// Structure: K_AB (L0+L1 two-phase) + gadd1 + L2dense + gadd2 + K_CD (L3+L4
// two-phase) + gadd4 + K_FG (L5+L6 two-phase) + gadd6. Output-space gather
// for L1/L2/L4/L6 (mean4 commutes with matmul). Row order m = 4n+b. f16 acts.

#define NN 55296
#define MM (NN * 4)   // 221184 rows

typedef unsigned short u16;
typedef _Float16 f16;
typedef f16 f16x8 __attribute__((ext_vector_type(8)));
typedef float f32x4 __attribute__((ext_vector_type(4)));
typedef u16 u16x8 __attribute__((ext_vector_type(8)));

__device__ inline u16 f2h(float f) { return __builtin_bit_cast(u16, (f16)f); }
__device__ inline float h2f(u16 u) { return (float)__builtin_bit_cast(f16, u); }

// ---------------------------------------------------------------- diagnostics
__global__ __launch_bounds__(256) void k_fill(float* __restrict__ p, float v, int total) {
  int i = blockIdx.x * 256 + threadIdx.x;
  if (i < total) p[i] = v;
}

// ---------------------------------------------------------------- input prep
__global__ __launch_bounds__(256) void k_prep_x(const float* __restrict__ in,
                                                u16* __restrict__ out) {
  int idx = blockIdx.x * 256 + threadIdx.x;
  int n = idx >> 5, b = (idx >> 3) & 3, f0 = (idx & 7) * 8;
  const float* p = in + ((long)b * NN + n) * 64 + f0;
  float4 v0 = *(const float4*)p, v1 = *(const float4*)(p + 4);
  u16x8 r;
  r[0] = f2h(v0.x); r[1] = f2h(v0.y); r[2] = f2h(v0.z); r[3] = f2h(v0.w);
  r[4] = f2h(v1.x); r[5] = f2h(v1.y); r[6] = f2h(v1.z); r[7] = f2h(v1.w);
  *(u16x8*)(out + (((long)n * 4 + b) * 64 + f0)) = r;
}

// ---------------------------------------------------------------- weight prep
// fused layout: dst[n][k'] = k'<K ? ws[k'][n] : wn[k'-K][n]  ([N][2K])
__global__ __launch_bounds__(256) void k_prep_w(const float* __restrict__ wsrc,
                                                const float* __restrict__ wnsrc,
                                                int K, int N, u16* __restrict__ dst) {
  int idx = blockIdx.x * 256 + threadIdx.x;
  int K2 = 2 * K;
  if (idx >= N * K2) return;
  int n = idx / K2, k = idx - n * K2;
  float v = (k < K) ? wsrc[(long)k * N + n] : wnsrc[(long)(k - K) * N + n];
  dst[(long)n * K2 + k] = f2h(v);
}

// dual layout: dst[r][k], r<N -> ws col r; r>=N -> wn col r-N  ([2N][K])
__global__ __launch_bounds__(256) void k_prep_w2(const float* __restrict__ wsrc,
                                                 const float* __restrict__ wnsrc,
                                                 int K, int N, u16* __restrict__ dst) {
  int idx = blockIdx.x * 256 + threadIdx.x;
  int total = 2 * N * K;
  if (idx >= total) return;
  int r = idx / K, k = idx - r * K;
  float v = (r < N) ? wsrc[(long)k * N + r] : wnsrc[(long)k * N + (r - N)];
  dst[idx] = f2h(v);
}

// ---------------------------------------------------------------- r8 SAGE/dense GEMM
template <int BM, int BN, int WM, int WN, typename TOUT, bool REMAP, bool GATHER>
__global__ __launch_bounds__(512, 4) void k_sage(
    const u16* __restrict__ X0, const u16* __restrict__ X1, int lda, int K0, int Ksum,
    const int4* __restrict__ src4, const u16* __restrict__ Wt,
    const float* __restrict__ bias, TOUT* __restrict__ OUT, long ldo,
    TOUT* __restrict__ OUT2, long ldo2, int Nsplit, int relu) {
  constexpr int GA = BM / 64;
  constexpr int GB = BN / 64;
  constexpr int NWM = BM / WM, NWN = BN / WN;
  static_assert(NWM * NWN == 8, "8 waves");
  constexpr int MF = WM / 16, NF = WN / 16;

  __shared__ __align__(16) u16 As[BM][64];
  __shared__ __align__(16) u16 Bs[BN][64];

  const int tid = threadIdx.x;
  const long m0 = (long)blockIdx.x * BM;
  const int n0 = blockIdx.y * BN;
  const int K2 = GATHER ? 2 * Ksum : Ksum;

  const int srow = tid >> 3;
  const int scg = tid & 7;

  int o_self[GA], o_g[GA][4];
#pragma unroll
  for (int i = 0; i < GA; ++i) {
    long m = m0 + srow + 64 * i;
    o_self[i] = (int)(m * lda);
    if constexpr (GATHER) {
      int b = (int)(m & 3);
      int4 s = src4[(int)(m >> 2)];
      o_g[i][0] = (s.x * 4 + b) * lda;
      o_g[i][1] = (s.y * 4 + b) * lda;
      o_g[i][2] = (s.z * 4 + b) * lda;
      o_g[i][3] = (s.w * 4 + b) * lda;
    }
  }
  long o_b[GB];
#pragma unroll
  for (int j = 0; j < GB; ++j) o_b[j] = (long)(n0 + srow + 64 * j) * K2 + scg * 8;

  u16x8 ra[GA][4];
  u16x8 rb[GB];

  const int w = tid >> 6, lane = tid & 63;
  const int wm = w % NWM, wn = w / NWM;
  const int mo = wm * WM, no = wn * WN;
  const int lr = lane & 15, lg = lane >> 4;

  f32x4 acc[MF][NF];
#pragma unroll
  for (int i = 0; i < MF; ++i)
#pragma unroll
    for (int j = 0; j < NF; ++j) {
      f32x4 z = {0.f, 0.f, 0.f, 0.f};
      acc[i][j] = z;
    }

  auto issue = [&](int kt) {
    const bool agg = GATHER && (kt >= Ksum);
    int cs = agg ? kt - Ksum : kt;
    const u16* Xp = X0;
    if (cs >= K0) { Xp = X1; cs -= K0; }
    const int cb = cs + scg * 8;
#pragma unroll
    for (int i = 0; i < GA; ++i) {
      if (agg) {
#pragma unroll
        for (int k = 0; k < 4; ++k)
          ra[i][k] = *(const u16x8*)(Xp + (long)o_g[i][k] + cb);
      } else {
        ra[i][0] = *(const u16x8*)(Xp + (long)o_self[i] + cb);
      }
    }
#pragma unroll
    for (int j = 0; j < GB; ++j)
      rb[j] = *(const u16x8*)(Wt + o_b[j] + kt);
  };
  auto commit = [&](bool agg) {
#pragma unroll
    for (int i = 0; i < GA; ++i) {
      const int row = srow + 64 * i;
      u16x8 v = ra[i][0];
      if (agg) {
        f16x8 s01 = __builtin_bit_cast(f16x8, ra[i][0]) + __builtin_bit_cast(f16x8, ra[i][1]);
        f16x8 s23 = __builtin_bit_cast(f16x8, ra[i][2]) + __builtin_bit_cast(f16x8, ra[i][3]);
        v = __builtin_bit_cast(u16x8, (s01 + s23) * (f16)0.25f);
      }
      *(u16x8*)&As[row][(scg ^ (row & 7)) * 8] = v;
    }
#pragma unroll
    for (int j = 0; j < GB; ++j) {
      const int row = srow + 64 * j;
      *(u16x8*)&Bs[row][(scg ^ (row & 7)) * 8] = rb[j];
    }
  };

  issue(0);
  for (int kt = 0; kt < K2; kt += 64) {
    commit(GATHER && kt >= Ksum);
    __syncthreads();
    const int nx = kt + 64;
    if (nx < K2) issue(nx);
#pragma unroll
    for (int ks = 0; ks < 2; ++ks) {
      f16x8 af[MF], bfr[NF];
#pragma unroll
      for (int i = 0; i < MF; ++i) {
        const int row = mo + i * 16 + lr;
        af[i] = __builtin_bit_cast(f16x8,
                  *(const u16x8*)&As[row][((ks * 4 + lg) ^ (row & 7)) * 8]);
      }
#pragma unroll
      for (int j = 0; j < NF; ++j) {
        const int row = no + j * 16 + lr;
        bfr[j] = __builtin_bit_cast(f16x8,
                   *(const u16x8*)&Bs[row][((ks * 4 + lg) ^ (row & 7)) * 8]);
      }
#pragma unroll
      for (int i = 0; i < MF; ++i)
#pragma unroll
        for (int j = 0; j < NF; ++j)
          acc[i][j] = __builtin_amdgcn_mfma_f32_16x16x32_f16(af[i], bfr[j], acc[i][j], 0, 0, 0);
    }
    __syncthreads();
  }

#pragma unroll
  for (int i = 0; i < MF; ++i)
#pragma unroll
    for (int j = 0; j < NF; ++j) {
      const int col = n0 + no + j * 16 + lr;
      const float bv = bias ? bias[col] : 0.f;
      TOUT* Op; long ld; int c;
      if (col < Nsplit) { Op = OUT; ld = ldo; c = col; }
      else              { Op = OUT2; ld = ldo2; c = col - Nsplit; }
#pragma unroll
      for (int r = 0; r < 4; ++r) {
        float v = acc[i][j][r] + bv;
        if (relu) v = fmaxf(v, 0.f);
        const long m = m0 + mo + i * 16 + lg * 4 + r;
        const long orow = REMAP ? ((m & 3) * (long)NN + (m >> 2)) : m;
        if constexpr (sizeof(TOUT) == 2) Op[orow * ld + c] = (TOUT)f2h(v);
        else                             Op[orow * ld + c] = v;
      }
    }
}

// ---------------------------------------------------------------- two-phase fusion (r8)
// Phase1: T(64 x N1) = relu( [X|mean4 gather X] @ W1t^T + bias1 )  (tile in LDS)
// Phase2: [OUT|OUT2] = [T | G2(own rows)] @ W2t^T                  (dual, no bias)
template <int N1, int KS1, int K2B, int N2, int NSPLIT>
__global__ __launch_bounds__(512, 4) void k_fuse2(
    const u16* __restrict__ X0, const u16* __restrict__ X1, int lda, int K0,
    const int4* __restrict__ src4,
    const u16* __restrict__ W1t, const float* __restrict__ bias1,
    const u16* __restrict__ G2, int ldg2,
    const u16* __restrict__ W2t,
    u16* __restrict__ OUT, long ldo, u16* __restrict__ OUT2, long ldo2) {
  constexpr int K21 = 2 * KS1;          // phase1 K (self + agg)
  constexpr int K22 = N1 + K2B;         // phase2 K
  constexpr int GB1 = N1 / 64, GB2 = N2 / 64;
  constexpr int BSROWS = (N1 > N2 ? N1 : N2);
  __shared__ __align__(16) u16 T[64][N1];
  __shared__ __align__(16) u16 As[64][64];
  __shared__ __align__(16) u16 Bs[BSROWS][64];

  const int tid = threadIdx.x;
  const long m0 = (long)blockIdx.x * 64;
  const int srow = tid >> 3, scg = tid & 7;
  const long mrow = m0 + srow;

  const int o_self = (int)(mrow * lda);
  const int bb = (int)(mrow & 3);
  const int4 s = src4[(int)(mrow >> 2)];
  const int og0 = (s.x * 4 + bb) * lda, og1 = (s.y * 4 + bb) * lda;
  const int og2 = (s.z * 4 + bb) * lda, og3 = (s.w * 4 + bb) * lda;

  const int w = tid >> 6, lane = tid & 63;
  const int lr = lane & 15, lg = lane >> 4;

  // ---------------- phase 1: fused gather GEMM -> T
  constexpr int NWN1 = N1 / 32, NWM1 = 8 / NWN1, WM1 = 64 / NWM1, MF1 = WM1 / 16;
  const int mo1 = (w % NWM1) * WM1, no1 = (w / NWM1) * 32;

  int ob1[GB1];
#pragma unroll
  for (int j = 0; j < GB1; ++j) ob1[j] = (srow + 64 * j) * K21 + scg * 8;

  u16x8 ra0, ra1, ra2, ra3, rb[GB1];

  auto issue1 = [&](int kt) {
    const bool agg = kt >= KS1;
    int cs = agg ? kt - KS1 : kt;
    const u16* Xp = X0;
    if (cs >= K0) { Xp = X1; cs -= K0; }
    const int cb = cs + scg * 8;
    if (agg) {
      ra0 = *(const u16x8*)(Xp + og0 + cb);
      ra1 = *(const u16x8*)(Xp + og1 + cb);
      ra2 = *(const u16x8*)(Xp + og2 + cb);
      ra3 = *(const u16x8*)(Xp + og3 + cb);
    } else {
      ra0 = *(const u16x8*)(Xp + o_self + cb);
    }
#pragma unroll
    for (int j = 0; j < GB1; ++j)
      rb[j] = *(const u16x8*)(W1t + ob1[j] + kt);
  };
  auto commit1 = [&](bool agg) {
    u16x8 v = ra0;
    if (agg) {
      f16x8 s01 = __builtin_bit_cast(f16x8, ra0) + __builtin_bit_cast(f16x8, ra1);
      f16x8 s23 = __builtin_bit_cast(f16x8, ra2) + __builtin_bit_cast(f16x8, ra3);
      v = __builtin_bit_cast(u16x8, (s01 + s23) * (f16)0.25f);
    }
    *(u16x8*)&As[srow][(scg ^ (srow & 7)) * 8] = v;
#pragma unroll
    for (int j = 0; j < GB1; ++j) {
      const int row = srow + 64 * j;
      *(u16x8*)&Bs[row][(scg ^ (row & 7)) * 8] = rb[j];
    }
  };

  f32x4 acc1[MF1][2];
#pragma unroll
  for (int i = 0; i < MF1; ++i) {
    f32x4 z = {0.f, 0.f, 0.f, 0.f};
    acc1[i][0] = z; acc1[i][1] = z;
  }

  issue1(0);
  for (int kt = 0; kt < K21; kt += 64) {
    commit1(kt >= KS1);
    __syncthreads();
    if (kt + 64 < K21) issue1(kt + 64);
#pragma unroll
    for (int ks = 0; ks < 2; ++ks) {
      f16x8 af[MF1], bf0, bf1;
#pragma unroll
      for (int i = 0; i < MF1; ++i) {
        const int row = mo1 + i * 16 + lr;
        af[i] = __builtin_bit_cast(f16x8,
                  *(const u16x8*)&As[row][((ks * 4 + lg) ^ (row & 7)) * 8]);
      }
      {
        const int row = no1 + lr;
        bf0 = __builtin_bit_cast(f16x8,
                *(const u16x8*)&Bs[row][((ks * 4 + lg) ^ (row & 7)) * 8]);
      }
      {
        const int row = no1 + 16 + lr;
        bf1 = __builtin_bit_cast(f16x8,
                *(const u16x8*)&Bs[row][((ks * 4 + lg) ^ (row & 7)) * 8]);
      }
#pragma unroll
      for (int i = 0; i < MF1; ++i) {
        acc1[i][0] = __builtin_amdgcn_mfma_f32_16x16x32_f16(af[i], bf0, acc1[i][0], 0, 0, 0);
        acc1[i][1] = __builtin_amdgcn_mfma_f32_16x16x32_f16(af[i], bf1, acc1[i][1], 0, 0, 0);
      }
    }
    __syncthreads();
  }

  // epilogue1: relu+bias -> T (granule-swizzled), C/D layout per m89
#pragma unroll
  for (int i = 0; i < MF1; ++i)
#pragma unroll
    for (int j = 0; j < 2; ++j) {
      const int col = no1 + j * 16 + lr;
      const float bv = bias1[col];
#pragma unroll
      for (int r = 0; r < 4; ++r) {
        float v = fmaxf(acc1[i][j][r] + bv, 0.f);
        const int row = mo1 + i * 16 + lg * 4 + r;
        T[row][(((col >> 3) ^ (row & 7)) << 3) | (col & 7)] = f2h(v);
      }
    }

  // ---------------- phase 2: dense dual GEMM [T | G2] @ W2t
  constexpr int NWN2 = N2 / 32, NWM2 = 8 / NWN2, WM2 = 64 / NWM2, MF2 = WM2 / 16;
  const int mo2 = (w % NWM2) * WM2, no2 = (w / NWM2) * 32;

  int ob2[GB2];
#pragma unroll
  for (int j = 0; j < GB2; ++j) ob2[j] = (srow + 64 * j) * K22 + scg * 8;
  const long oG = (K2B > 0) ? (mrow * (long)ldg2 + scg * 8) : 0;

  u16x8 rb2[GB2], rg;

  auto issue2 = [&](int kt) {
#pragma unroll
    for (int j = 0; j < GB2; ++j)
      rb2[j] = *(const u16x8*)(W2t + ob2[j] + kt);
    if constexpr (K2B > 0) {
      if (kt >= N1) rg = *(const u16x8*)(G2 + oG + (kt - N1));
    }
  };
  auto commit2 = [&](int kt) {
#pragma unroll
    for (int j = 0; j < GB2; ++j) {
      const int row = srow + 64 * j;
      *(u16x8*)&Bs[row][(scg ^ (row & 7)) * 8] = rb2[j];
    }
    if constexpr (K2B > 0) {
      if (kt >= N1) *(u16x8*)&As[srow][(scg ^ (srow & 7)) * 8] = rg;
    }
  };

  f32x4 acc2[MF2][2];
#pragma unroll
  for (int i = 0; i < MF2; ++i) {
    f32x4 z = {0.f, 0.f, 0.f, 0.f};
    acc2[i][0] = z; acc2[i][1] = z;
  }

  issue2(0);
  for (int kt = 0; kt < K22; kt += 64) {
    commit2(kt);
    __syncthreads();                     // first iter also publishes T
    if (kt + 64 < K22) issue2(kt + 64);
    const bool fromT = kt < N1;
#pragma unroll
    for (int ks = 0; ks < 2; ++ks) {
      f16x8 af[MF2], bf0, bf1;
#pragma unroll
      for (int i = 0; i < MF2; ++i) {
        const int row = mo2 + i * 16 + lr;
        if (fromT) {
          const int g = (kt >> 3) + ks * 4 + lg;
          af[i] = __builtin_bit_cast(f16x8,
                    *(const u16x8*)&T[row][(g ^ (row & 7)) * 8]);
        } else {
          af[i] = __builtin_bit_cast(f16x8,
                    *(const u16x8*)&As[row][((ks * 4 + lg) ^ (row & 7)) * 8]);
        }
      }
      {
        const int row = no2 + lr;
        bf0 = __builtin_bit_cast(f16x8,
                *(const u16x8*)&Bs[row][((ks * 4 + lg) ^ (row & 7)) * 8]);
      }
      {
        const int row = no2 + 16 + lr;
        bf1 = __builtin_bit_cast(f16x8,
                *(const u16x8*)&Bs[row][((ks * 4 + lg) ^ (row & 7)) * 8]);
      }
#pragma unroll
      for (int i = 0; i < MF2; ++i) {
        acc2[i][0] = __builtin_amdgcn_mfma_f32_16x16x32_f16(af[i], bf0, acc2[i][0], 0, 0, 0);
        acc2[i][1] = __builtin_amdgcn_mfma_f32_16x16x32_f16(af[i], bf1, acc2[i][1], 0, 0, 0);
      }
    }
    __syncthreads();
  }

  // epilogue2: split-routed store, no bias/relu (applied in k_gadd)
#pragma unroll
  for (int i = 0; i < MF2; ++i)
#pragma unroll
    for (int j = 0; j < 2; ++j) {
      const int col = no2 + j * 16 + lr;
      u16* Op; long ld; int c;
      if (col < NSPLIT) { Op = OUT; ld = ldo; c = col; }
      else              { Op = OUT2; ld = ldo2; c = col - NSPLIT; }
#pragma unroll
      for (int r = 0; r < 4; ++r) {
        const long m = m0 + mo2 + i * 16 + lg * 4 + r;
        Op[m * ld + c] = f2h(acc2[i][j][r]);
      }
    }
}

// ---------------------------------------------------------------- gather-add pass
template <typename TOUT, bool REMAP, bool RELU, int GSH>
__global__ __launch_bounds__(256) void k_gadd(
    const u16* __restrict__ Y, long ldy, const u16* __restrict__ Z, long ldz,
    const int4* __restrict__ src4, const float* __restrict__ bias,
    TOUT* __restrict__ OUT, long ldo) {
  const int idx = blockIdx.x * 256 + threadIdx.x;
  const int g = idx & ((1 << GSH) - 1);
  const long m = idx >> GSH;
  const int b = (int)(m & 3), n = (int)(m >> 2);
  const int4 s = src4[n];
  u16x8 ys = *(const u16x8*)(Y + m * ldy + g * 8);
  u16x8 z0 = *(const u16x8*)(Z + (long)(s.x * 4 + b) * ldz + g * 8);
  u16x8 z1 = *(const u16x8*)(Z + (long)(s.y * 4 + b) * ldz + g * 8);
  u16x8 z2 = *(const u16x8*)(Z + (long)(s.z * 4 + b) * ldz + g * 8);
  u16x8 z3 = *(const u16x8*)(Z + (long)(s.w * 4 + b) * ldz + g * 8);
  float4 bv0 = *(const float4*)(bias + g * 8);
  float4 bv1 = *(const float4*)(bias + g * 8 + 4);
  float o[8];
#pragma unroll
  for (int j = 0; j < 8; ++j) {
    float bj = (j < 4) ? (&bv0.x)[j] : (&bv1.x)[j - 4];
    float v = h2f(ys[j]) + 0.25f * (h2f(z0[j]) + h2f(z1[j]) + h2f(z2[j]) + h2f(z3[j])) + bj;
    o[j] = RELU ? fmaxf(v, 0.f) : v;
  }
  const long orow = REMAP ? ((long)b * NN + n) : m;
  if constexpr (sizeof(TOUT) == 2) {
    u16x8 r;
#pragma unroll
    for (int j = 0; j < 8; ++j) r[j] = f2h(o[j]);
    *(u16x8*)(OUT + orow * ldo + g * 8) = r;
  } else {
#pragma unroll
    for (int j = 0; j < 8; ++j) OUT[orow * ldo + g * 8 + j] = o[j];
  }
}

// ---------------------------------------------------------------- host driver
extern "C" void kernel_launch(void* const* d_in, const int* in_sizes, int n_in,
                              void* d_out, int out_size, void* d_ws, size_t ws_size,
                              hipStream_t stream) {
  const float* inputs = (const float*)d_in[0];
  const int*   src    = (const int*)d_in[1];
  const float* W[6][3];
  for (int i = 0; i < 6; ++i) {
    W[i][0] = (const float*)d_in[3 + 3 * i];
    W[i][1] = (const float*)d_in[4 + 3 * i];
    W[i][2] = (const float*)d_in[5 + 3 * i];
  }

  const long M = (long)MM;
  const int dims[6][2] = {{64,256},{256,128},{128,64},{64,64},{128,128},{256,64}};
  long wo[6]; long wtot = 0;
  for (int i = 0; i < 6; ++i) { wo[i] = wtot; wtot += (long)dims[i][1] * 2 * dims[i][0]; }
  const long woD3 = wtot;               // dual layout of weight 3 ([128][64])
  wtot += 2L * dims[3][1] * dims[3][0];

  const size_t needed = ((size_t)384 * M + wtot) * sizeof(u16);
  if (ws_size < needed) {
    float mb = (float)(ws_size >> 20);   // diagnostic: absmax ~= ws MiB
    k_fill<<<(out_size + 255) / 256, 256, 0, stream>>>((float*)d_out, mb, out_size);
    return;
  }

  u16* act = (u16*)d_ws;
  // slab plan (f16 cols of M), lifetimes audited disjoint (r12, proven):
  u16* Y1  = act + 0 * M;     // [M][128] K_AB out; becomes H2 in-place
  u16* H2  = act + 0 * M;     // [M][128] gadd1 -> K_FG phase2
  u16* Z1  = act + 128 * M;   // [M][128] K_AB out, dead after gadd1
  u16* YZ2 = act + 128 * M;   // [M][128] L2dense -> gadd2 (over Z1)
  u16* Z4  = act + 128 * M;   // [M][64]  K_CD out (YZ2 dead after gadd2)
  u16* Y6  = act + 128 * M;   // [M][64]  K_FG out (Z4 dead after gadd4)
  u16* H5a = act + 192 * M;   // [M][64]  gadd4 -> K_FG (YZ2 upper half dead)
  u16* H3  = act + 256 * M;   // [M][64]  gadd2 -> K_CD/K_FG
  u16* Xb  = act + 320 * M;   // [M][64]  f16 input (step0; dead after K_AB)
  u16* Y4  = act + 320 * M;   // [M][64]  K_CD out (over Xb)
  u16* Z6  = act + 320 * M;   // [M][64]  K_FG out (Y4 dead after gadd4)
  u16* WT  = act + 384 * M;   // packed weights
  u16* Xp  = (u16*)d_out;     // [M][64]  x' between steps (d_out scratch)
  const int4* src4 = (const int4*)src;

  k_prep_x<<<NN * 32 / 256, 256, 0, stream>>>(inputs, Xb);
  for (int i : {0, 3, 4}) {   // fused layouts (gather-phase B operands)
    int total = dims[i][1] * 2 * dims[i][0];
    k_prep_w<<<(total + 255) / 256, 256, 0, stream>>>(W[i][0], W[i][1], dims[i][0],
                                                      dims[i][1], WT + wo[i]);
  }
  for (int i : {1, 2, 5}) {   // dual layouts (dense dual GEMMs)
    int total = 2 * dims[i][1] * dims[i][0];
    k_prep_w2<<<(total + 255) / 256, 256, 0, stream>>>(W[i][0], W[i][1], dims[i][0],
                                                       dims[i][1], WT + wo[i]);
  }
  {  // dual layout of weight 3 for K_CD phase2
    int total = 2 * dims[3][1] * dims[3][0];
    k_prep_w2<<<(total + 255) / 256, 256, 0, stream>>>(W[3][0], W[3][1], dims[3][0],
                                                       dims[3][1], WT + woD3);
  }

  const int BIG = 1 << 30;
  const dim3 g1(MM / 128, 1);
  for (int step = 0; step < 2; ++step) {
    const u16* x0 = step ? Xp : Xb;
    // K_AB: L0 (x -> h1 tile, relu+b0) + L1 dense dual -> Y1 | Z1
    k_fuse2<256, 64, 0, 256, 128><<<MM / 64, 512, 0, stream>>>(
        x0, x0, 64, 64, src4, WT + wo[0], W[0][2],
        nullptr, 0, WT + wo[1], Y1, 128, Z1, 128);
    // gadd1: H2 = relu(Y1 + mean4 Z1[g] + b1)   (in-place over Y1)
    k_gadd<u16, false, true, 4><<<MM * 16 / 256, 256, 0, stream>>>(
        Y1, 128, Z1, 128, src4, W[1][2], H2, 128);
    // L2 dense dual: H2 -> YZ2 [Y|Z]
    k_sage<128, 128, 64, 32, u16, false, false><<<g1, 512, 0, stream>>>(
        H2, H2, 128, 128, 128, src4, WT + wo[2], nullptr, YZ2, 128,
        (u16*)nullptr, 0, BIG, 0);
    // gadd2: H3 = relu(Y + mean4 Z[g] + b2)
    k_gadd<u16, false, true, 3><<<MM * 8 / 256, 256, 0, stream>>>(
        YZ2, 128, YZ2 + 64, 128, src4, W[2][2], H3, 64);
    // K_CD: L3 (h3 -> h4 tile, relu+b3) + L4 dense dual h4@[Ws4|Wn4] -> Y4 | Z4
    k_fuse2<64, 64, 0, 128, 64><<<MM / 64, 512, 0, stream>>>(
        H3, H3, 64, 64, src4, WT + wo[3], W[3][2],
        nullptr, 0, WT + woD3, Y4, 64, Z4, 64);
    // gadd4: H5a = relu(Y4 + mean4 Z4[g] + b4)
    k_gadd<u16, false, true, 3><<<MM * 8 / 256, 256, 0, stream>>>(
        Y4, 64, Z4, 64, src4, W[3][2], H5a, 64);
    // K_FG: L5 ([h5a|h3] -> h6a tile, relu+b4) + L6 dense dual [tile|H2] -> Y6 | Z6
    k_fuse2<128, 128, 128, 128, 64><<<MM / 64, 512, 0, stream>>>(
        H5a, H3, 64, 64, src4, WT + wo[4], W[4][2],
        H2, 128, WT + wo[5], Y6, 64, Z6, 64);
    // gadd6: x' = Y6 + mean4 Z6[g] + b6  (no relu)
    if (step == 0)
      k_gadd<u16, false, false, 3><<<MM * 8 / 256, 256, 0, stream>>>(
          Y6, 64, Z6, 64, src4, W[5][2], Xp, 64);
    else
      k_gadd<float, true, false, 3><<<MM * 8 / 256, 256, 0, stream>>>(
          Y6, 64, Z6, 64, src4, W[5][2], (float*)d_out, 64);
  }
}